// Round 19
// baseline (367.530 us; speedup 1.0000x reference)
//
#include <hip/hip_runtime.h>
#include <hip/hip_bf16.h>
#include <math.h>

#define NB 256
#define NN 400
#define NH 128
#define NCOUT 16
#define NNP 416   // padded N (13*32 = 52*8)
#define KP  416   // padded K for W_adj prep

static constexpr float LOGIT_THRESH = 0.40546510810816444f; // ln(1.5)
static constexpr float LN_EPS = 1e-5f;

typedef __attribute__((ext_vector_type(8))) short short8v;
typedef __attribute__((ext_vector_type(4))) float f32x4;

static __device__ __forceinline__ short f2bf_rne(float f) {
    unsigned u = __float_as_uint(f);
    unsigned r = (u + 0x7fff + ((u >> 16) & 1)) >> 16;
    return (short)r;
}

// packed f32 pair -> 2x bf16 (RNE) in one v_cvt_pk_bf16_f32
static __device__ __forceinline__ unsigned pk_bf16(float a, float b) {
    __hip_bfloat162 h = __float22bfloat162_rn(make_float2(a, b));
    unsigned r;
    __builtin_memcpy(&r, &h, 4);
    return r;
}
// hi-only conversion of 8 floats -> 8 bf16 (4 cvt_pk)
static __device__ __forceinline__ void cvt8v(const float x[8], short8v& hv) {
    unsigned* hp = (unsigned*)&hv;
#pragma unroll
    for (int q = 0; q < 4; ++q) hp[q] = pk_bf16(x[2 * q], x[2 * q + 1]);
}

// async global->LDS DMA, 16B per lane; lptr is wave-uniform base, HW adds lane*16
static __device__ __forceinline__ void gload16(const void* g, void* l) {
    __builtin_amdgcn_global_load_lds((const __attribute__((address_space(1))) void*)g,
                                     (__attribute__((address_space(3))) void*)l, 16, 0, 0);
}

// ---------------- W_adj -> bf16 (hi only), transposed + padded ----------------
__global__ __launch_bounds__(256) void k_wprep(const float* __restrict__ W,
                                               short* __restrict__ WtH)
{
    const int k0 = blockIdx.x * 32, d0 = blockIdx.y * 32;
    __shared__ float tile[32][33];
    const int t = threadIdx.x, cc = t & 31, rr = t >> 5;
#pragma unroll
    for (int i = 0; i < 4; ++i) {
        int k = k0 + rr + i * 8, d = d0 + cc;
        tile[rr + i * 8][cc] = (k < NN && d < NN) ? W[k * NN + d] : 0.f;
    }
    __syncthreads();
#pragma unroll
    for (int i = 0; i < 4; ++i) {
        int dr = rr + i * 8;
        int d = d0 + dr, k = k0 + cc;
        WtH[d * KP + k] = f2bf_rne(tile[cc][dr]);
    }
}

// ---------------- W (128x128) -> bf16 transposed: WT[h][k] ----------------
__global__ __launch_bounds__(256) void k_wprepW(const float* __restrict__ W,
                                                short* __restrict__ WTH)
{
    const int t = blockIdx.x * 256 + threadIdx.x;   // 16384
    const int h = t >> 7, k = t & 127;
    WTH[h * NH + k] = f2bf_rne(W[k * NH + h]);
}

// ---------------- mask GEMM -> tiled maskT[b][dg][sc][16][8], hi-only bf16 ----------------
// r13 structure + wave-uniform fragment-count guards (skip padding-only fragments:
// s0==384 -> only wm==0/m==0 rows valid; d0==384 -> only wn==0/n==0 cols valid).
__global__ __launch_bounds__(256) void k_mask(const float* __restrict__ adj,
                                              const short* __restrict__ WtH,
                                              const float* __restrict__ badj,
                                              unsigned char* __restrict__ maskT)
{
    const int j   = blockIdx.x;
    const int xcd = j & 7;
    const int li  = j >> 3;
    const int panel  = xcd * 128 + (li >> 2);
    const int member = li & 3;
    const int b  = panel >> 2;
    const int s0 = (panel & 3) * 128;
    const int d0 = member * 128;

    const int t = threadIdx.x;
    const int lane = t & 63, w = t >> 6;
    const int wm = w >> 1, wn = w & 1;
    const int fr = lane & 15, fc = lane >> 4;

    // valid fragment counts for this wave (all wave-uniform)
    const int mval = (s0 == 384) ? (wm == 0 ? 1 : 0) : 4;
    const int nval = (d0 == 384) ? (wn == 0 ? 1 : 0) : 4;

    __shared__ float As[2][128 * 32];
    __shared__ short Bhs[2][128 * 32];

    const float* adjb = adj + (long)b * NN * NN;

    long aG[4];
    int  aRow[4];
#pragma unroll
    for (int i = 0; i < 4; ++i) {
        int rloc = w * 32 + i * 8 + (lane >> 3);
        aRow[i] = rloc;
        int srow = s0 + rloc; srow = srow < NN ? srow : NN - 1;
        int c = (lane & 7) ^ (rloc & 7);
        aG[i] = (long)srow * NN + c * 4;
    }
    long bG[2];
#pragma unroll
    for (int i = 0; i < 2; ++i) {
        int rloc = w * 32 + i * 16 + (lane >> 2);
        int drow = d0 + rloc;
        int c = (lane & 3) ^ ((rloc >> 1) & 3);
        bG[i] = (long)drow * KP + c * 8;
    }

    f32x4 acc[4][4];
#pragma unroll
    for (int mi = 0; mi < 4; ++mi)
#pragma unroll
        for (int ni = 0; ni < 4; ++ni) acc[mi][ni] = (f32x4){0.f, 0.f, 0.f, 0.f};

    const int ca0 = (2 * fc) ^ (fr & 7);
    const int ca1 = (2 * fc + 1) ^ (fr & 7);
    const int cb  = fc ^ ((fr >> 1) & 3);

    #define STAGE(KT, BUF)                                                            \
    do {                                                                              \
        const int k0_ = (KT) * 32;                                                    \
        _Pragma("unroll")                                                             \
        for (int i = 0; i < 4; ++i) {                                                 \
            long gi = aG[i] + k0_;                                                    \
            if ((KT) == 12) {                                                         \
                int c = (lane & 7) ^ (aRow[i] & 7);                                   \
                if (c >= 4) gi = aG[i] - (long)c * 4;                                 \
            }                                                                         \
            gload16(adjb + gi, (char*)&As[BUF][0] + (w * 32 + i * 8) * 128);          \
        }                                                                             \
        _Pragma("unroll")                                                             \
        for (int i = 0; i < 2; ++i) {                                                 \
            gload16(WtH + bG[i] + k0_, (char*)&Bhs[BUF][0] + (w * 32 + i * 16) * 64); \
        }                                                                             \
    } while (0)

    STAGE(0, 0);
    asm volatile("s_waitcnt vmcnt(0)" ::: "memory");
    __builtin_amdgcn_s_barrier();

    int cur = 0;
    for (int kt = 0; kt < 13; ++kt) {
        __builtin_amdgcn_s_barrier();
        if (kt < 12) STAGE(kt + 1, cur ^ 1);
        if (kt < 12) asm volatile("s_waitcnt vmcnt(6)" ::: "memory");
        else         asm volatile("s_waitcnt vmcnt(0)" ::: "memory");
        __builtin_amdgcn_s_barrier();
        __builtin_amdgcn_sched_barrier(0);

        short8v ah[4], bh[4];
#pragma unroll
        for (int m = 0; m < 4; ++m) {
            if (m < mval) {
                const int row = wm * 64 + m * 16 + fr;
                float4 u0 = *(const float4*)((const char*)&As[cur][0] + row * 128 + ca0 * 16);
                float4 u1 = *(const float4*)((const char*)&As[cur][0] + row * 128 + ca1 * 16);
                float x[8] = {u0.x, u0.y, u0.z, u0.w, u1.x, u1.y, u1.z, u1.w};
                cvt8v(x, ah[m]);
            }
        }
#pragma unroll
        for (int n = 0; n < 4; ++n) {
            if (n < nval) {
                const int row = wn * 64 + n * 16 + fr;
                bh[n] = *(const short8v*)((const char*)&Bhs[cur][0] + row * 64 + cb * 16);
            }
        }
#pragma unroll
        for (int mi = 0; mi < 4; ++mi) {
            if (mi < mval) {
#pragma unroll
                for (int ni = 0; ni < 4; ++ni) {
                    if (ni < nval)
                        acc[mi][ni] = __builtin_amdgcn_mfma_f32_16x16x32_bf16(ah[mi], bh[ni], acc[mi][ni], 0, 0, 0);
                }
            }
        }
        cur ^= 1;
    }
    #undef STAGE

    // epilogue -> tiled maskT[b][dg][sc][16][8]
    // (skipped fragments: acc stays zero -> pad mask bytes written as 0, which
    //  matches the pre-guard behavior since s>=NN / d>=NN guards force 0 anyway)
    unsigned char* mTb = maskT + (long)b * 32 * 52 * 128;
    const int dgbase = (d0 >> 4) + wn * 4;
    const int scbase = ((s0 + wm * 64) >> 3) + (fc >> 1);
    const int off8   = (fc & 1) * 4;
#pragma unroll
    for (int ni = 0; ni < 4; ++ni) {
        const int d = d0 + wn * 64 + ni * 16 + fr;
        if (d >= NN) continue;
        const float bv = badj[d];
#pragma unroll
        for (int mi = 0; mi < 4; ++mi) {
            const int s_cb = s0 + wm * 64 + mi * 16 + fc * 4;
            if (s_cb >= NNP) continue;
            uchar4 pk;
#pragma unroll
            for (int jj = 0; jj < 4; ++jj) {
                const int s = s_cb + jj;
                bool v = (s < NN) && ((acc[mi][ni][jj] + bv) > LOGIT_THRESH || s == d);
                ((unsigned char*)&pk)[jj] = v ? 1 : 0;
            }
            *(uchar4*)&mTb[((long)(dgbase + ni) * 52 + (scbase + mi * 2)) * 128 + fr * 8 + off8] = pk;
        }
    }
}

// ---------------- hpT (TILED [b][sc][h][8]) = (hin @ W)^T bf16 + FUSED exp tables ----------------
__global__ __launch_bounds__(256) void k_hp(const float* __restrict__ hin,
                                            const short* __restrict__ WTH,
                                            const float* __restrict__ asrc,
                                            const float* __restrict__ adst,
                                            short* __restrict__ hpT,
                                            float* __restrict__ e1sA, float* __restrict__ e2sA,
                                            float* __restrict__ e1dA, float* __restrict__ e2dA)
{
    const int b  = blockIdx.y;
    const int s0 = blockIdx.x * 128;
    const int t  = threadIdx.x;
    const int lane = t & 63, w = t >> 6;
    const int wm = w >> 1, wn = w & 1;
    const int fr = lane & 15, fc = lane >> 4;

    const float* hb = hin + (long)b * NN * NH;
    short* hpTb = hpT + (long)b * 52 * 128 * 8;

    f32x4 acc[4][4];
#pragma unroll
    for (int m = 0; m < 4; ++m)
#pragma unroll
        for (int n = 0; n < 4; ++n) acc[m][n] = (f32x4){0.f, 0.f, 0.f, 0.f};

    for (int kt = 0; kt < 4; ++kt) {
        const int k0 = kt * 32;
        short8v ah[4], bh[4];
#pragma unroll
        for (int m = 0; m < 4; ++m) {
            const int h = wm * 64 + m * 16 + fr;
            ah[m] = *(const short8v*)&WTH[h * NH + k0 + fc * 8];
        }
#pragma unroll
        for (int n = 0; n < 4; ++n) {
            const int s = s0 + wn * 64 + n * 16 + fr;
            float x[8];
            if (s < NN) {
                float4 u0 = *(const float4*)&hb[(long)s * NH + k0 + fc * 8];
                float4 u1 = *(const float4*)&hb[(long)s * NH + k0 + fc * 8 + 4];
                x[0]=u0.x; x[1]=u0.y; x[2]=u0.z; x[3]=u0.w;
                x[4]=u1.x; x[5]=u1.y; x[6]=u1.z; x[7]=u1.w;
            } else {
#pragma unroll
                for (int jj = 0; jj < 8; ++jj) x[jj] = 0.f;
            }
            cvt8v(x, bh[n]);
        }
#pragma unroll
        for (int m = 0; m < 4; ++m)
#pragma unroll
            for (int n = 0; n < 4; ++n)
                acc[m][n] = __builtin_amdgcn_mfma_f32_16x16x32_bf16(ah[m], bh[n], acc[m][n], 0, 0, 0);
    }

    // store: tiled layout [sc][h][8]
#pragma unroll
    for (int m = 0; m < 4; ++m) {
#pragma unroll
        for (int n = 0; n < 4; ++n) {
            const int s = s0 + wn * 64 + n * 16 + fr;
            if (s >= NNP) continue;
            const int sc = s >> 3, so = s & 7;
#pragma unroll
            for (int jj = 0; jj < 4; ++jj) {
                const int h = wm * 64 + m * 16 + fc * 4 + jj;
                hpTb[((long)sc * 128 + h) * 8 + so] = f2bf_rne(acc[m][n][jj]);
            }
        }
    }

    __shared__ float esp[2][128], edp[2][128];
    float asv[4][4], adv[4][4];
#pragma unroll
    for (int m = 0; m < 4; ++m)
#pragma unroll
        for (int jj = 0; jj < 4; ++jj) {
            const int h = wm * 64 + m * 16 + fc * 4 + jj;
            asv[m][jj] = asrc[h];
            adv[m][jj] = adst[h];
        }
    float ps[4] = {0.f, 0.f, 0.f, 0.f}, pd[4] = {0.f, 0.f, 0.f, 0.f};
#pragma unroll
    for (int n = 0; n < 4; ++n)
#pragma unroll
        for (int m = 0; m < 4; ++m)
#pragma unroll
            for (int jj = 0; jj < 4; ++jj) {
                ps[n] += acc[m][n][jj] * asv[m][jj];
                pd[n] += acc[m][n][jj] * adv[m][jj];
            }
#pragma unroll
    for (int n = 0; n < 4; ++n) {
        ps[n] += __shfl_xor(ps[n], 16); ps[n] += __shfl_xor(ps[n], 32);
        pd[n] += __shfl_xor(pd[n], 16); pd[n] += __shfl_xor(pd[n], 32);
    }
    if (fc == 0) {
#pragma unroll
        for (int n = 0; n < 4; ++n) {
            esp[wm][wn * 64 + n * 16 + fr] = ps[n];
            edp[wm][wn * 64 + n * 16 + fr] = pd[n];
        }
    }
    __syncthreads();
    if (t < 128) {
        const int s = s0 + t;
        if (s < NNP) {
            const float es = esp[0][t] + esp[1][t];
            const float ed = edp[0][t] + edp[1][t];
            const long o = (long)b * NNP + s;
            e1sA[o] = __expf(es);       e2sA[o] = __expf(0.2f * es);
            e1dA[o] = __expf(ed);       e2dA[o] = __expf(0.2f * ed);
        }
    }
}

// ---------------- MFMA aggregation v3: tiled-coalesced hpT reads; DO_LN=0 -> fused pool ----------------
template<int DO_LN>
__global__ __launch_bounds__(256) void k_aggr(const unsigned char* __restrict__ maskT,
                                              const short* __restrict__ hpT,
                                              const float* __restrict__ e1sA,
                                              const float* __restrict__ e2sA,
                                              const float* __restrict__ e1dA,
                                              const float* __restrict__ e2dA,
                                              const float* __restrict__ bias,
                                              const float* __restrict__ lng,
                                              const float* __restrict__ lnb,
                                              float* __restrict__ hout,
                                              float* __restrict__ partial)
{
    const int b  = blockIdx.y;
    const int bx = blockIdx.x;
    const int d0 = bx * 128;
    const int t  = threadIdx.x;
    const int lane = t & 63, w = t >> 6;       // w = d-quarter
    const int fr = lane & 15, fc = lane >> 4;

    __shared__ float e1s_l[NNP], e2s_l[NNP];
    __shared__ float den_l[128];
    __shared__ float lngl[128], lnbl[128];
    __shared__ float wsum[4][128];

    for (int i = t; i < NNP; i += 256) {
        const long o = (long)b * NNP + i;
        e1s_l[i] = e1sA[o];
        e2s_l[i] = e2sA[o];
    }
    if (DO_LN && t < 128) { lngl[t] = lng[t]; lnbl[t] = lnb[t]; }

    float e1dv[2], e2dv[2];
#pragma unroll
    for (int m = 0; m < 2; ++m) {
        const int d = d0 + w * 32 + m * 16 + fr;
        const bool v = d < NN;
        const long o = (long)b * NNP + (v ? d : 0);
        e1dv[m] = v ? e1dA[o] : 0.f;
        e2dv[m] = v ? e2dA[o] : 0.f;
    }
    __syncthreads();

    f32x4 acc[2][8];
#pragma unroll
    for (int m = 0; m < 2; ++m)
#pragma unroll
        for (int n = 0; n < 8; ++n) acc[m][n] = (f32x4){0.f, 0.f, 0.f, 0.f};
    float den[2] = {0.f, 0.f};

    const unsigned char* mbase = maskT + (((long)b * 32 + (d0 >> 4) + w * 2) * 52) * 128 + fr * 8;
    const short* hTb = hpT + (long)b * 52 * 128 * 8;

    for (int kt = 0; kt < 13; ++kt) {
        const int sb = kt * 32 + fc * 8;
        const short* tb = hTb + (long)(kt * 4 + fc) * 128 * 8;   // tile sc = kt*4+fc
        short8v bf_[8];
#pragma unroll
        for (int n = 0; n < 8; ++n)
            bf_[n] = *(const short8v*)&tb[(n * 16 + fr) * 8];    // 256B/16-lane group
        float4 e1a = *(const float4*)&e1s_l[sb];
        float4 e1b = *(const float4*)&e1s_l[sb + 4];
        float4 e2a = *(const float4*)&e2s_l[sb];
        float4 e2b = *(const float4*)&e2s_l[sb + 4];
        float e18[8] = {e1a.x, e1a.y, e1a.z, e1a.w, e1b.x, e1b.y, e1b.z, e1b.w};
        float e28[8] = {e2a.x, e2a.y, e2a.z, e2a.w, e2b.x, e2b.y, e2b.z, e2b.w};
        const long scoff = (long)(kt * 4 + fc) * 128;
#pragma unroll
        for (int m = 0; m < 2; ++m) {
            const unsigned long long mk = *(const unsigned long long*)(mbase + (long)m * 52 * 128 + scoff);
            short8v pv;
            unsigned* pw = (unsigned*)&pv;
#pragma unroll
            for (int q = 0; q < 4; ++q) {
                float p0 = fmaxf(e18[2 * q] * e1dv[m],     e28[2 * q] * e2dv[m]);
                float p1 = fmaxf(e18[2 * q + 1] * e1dv[m], e28[2 * q + 1] * e2dv[m]);
                p0 = ((mk >> (16 * q)) & 0xffULL)     ? p0 : 0.f;
                p1 = ((mk >> (16 * q + 8)) & 0xffULL) ? p1 : 0.f;
                den[m] += p0 + p1;
                pw[q] = pk_bf16(p0, p1);
            }
#pragma unroll
            for (int n = 0; n < 8; ++n)
                acc[m][n] = __builtin_amdgcn_mfma_f32_16x16x32_bf16(pv, bf_[n], acc[m][n], 0, 0, 0);
        }
    }

#pragma unroll
    for (int m = 0; m < 2; ++m) {
        den[m] += __shfl_xor(den[m], 16);
        den[m] += __shfl_xor(den[m], 32);
    }
    if (fc == 0) {
#pragma unroll
        for (int m = 0; m < 2; ++m) den_l[w * 32 + m * 16 + fr] = den[m];
    }
    __syncthreads();

    float bvh[8], lgv[8], lbv[8];
#pragma unroll
    for (int n = 0; n < 8; ++n) {
        bvh[n] = bias[n * 16 + fr];
        if (DO_LN) { lgv[n] = lngl[n * 16 + fr]; lbv[n] = lnbl[n * 16 + fr]; }
    }

    float* hb = hout + (long)b * NN * NH;

    if (DO_LN) {
#pragma unroll
        for (int m = 0; m < 2; ++m) {
#pragma unroll
            for (int jj = 0; jj < 4; ++jj) {
                const int dl = w * 32 + m * 16 + fc * 4 + jj;
                const int d = d0 + dl;
                const float idn = 1.f / den_l[dl];
                float v[8];
                float s1 = 0.f, s2 = 0.f;
#pragma unroll
                for (int n = 0; n < 8; ++n) {
                    v[n] = acc[m][n][jj] * idn + bvh[n];
                    s1 += v[n];
                    s2 += v[n] * v[n];
                }
                s1 += __shfl_xor(s1, 1); s2 += __shfl_xor(s2, 1);
                s1 += __shfl_xor(s1, 2); s2 += __shfl_xor(s2, 2);
                s1 += __shfl_xor(s1, 4); s2 += __shfl_xor(s2, 4);
                s1 += __shfl_xor(s1, 8); s2 += __shfl_xor(s2, 8);
                const float mean = s1 * (1.f / 128.f);
                const float var  = s2 * (1.f / 128.f) - mean * mean;
                const float inv  = rsqrtf(fmaxf(var, 0.f) + LN_EPS);
                if (d < NN) {
                    float* po = hb + (long)d * NH;
#pragma unroll
                    for (int n = 0; n < 8; ++n)
                        po[n * 16 + fr] = fmaxf((v[n] - mean) * inv * lgv[n] + lbv[n], 0.f);
                }
            }
        }
    } else {
        float psum[8] = {0.f, 0.f, 0.f, 0.f, 0.f, 0.f, 0.f, 0.f};
#pragma unroll
        for (int m = 0; m < 2; ++m) {
#pragma unroll
            for (int jj = 0; jj < 4; ++jj) {
                const int dl = w * 32 + m * 16 + fc * 4 + jj;
                const int d = d0 + dl;
                if (d >= NN) continue;
                const float idn = 1.f / den_l[dl];
#pragma unroll
                for (int n = 0; n < 8; ++n)
                    psum[n] += acc[m][n][jj] * idn + bvh[n];
            }
        }
#pragma unroll
        for (int n = 0; n < 8; ++n) {
            psum[n] += __shfl_xor(psum[n], 16);
            psum[n] += __shfl_xor(psum[n], 32);
        }
        if (fc == 0) {
#pragma unroll
            for (int n = 0; n < 8; ++n) wsum[w][n * 16 + fr] = psum[n];
        }
        __syncthreads();
        if (t < 128)
            partial[((long)b * 4 + bx) * 128 + t] =
                wsum[0][t] + wsum[1][t] + wsum[2][t] + wsum[3][t];
    }
}

// ---------------- final: mean over N (from partials) + linear ----------------
__global__ __launch_bounds__(128) void k_pool2(const float* __restrict__ partial,
                                               const float* __restrict__ Wl,
                                               const float* __restrict__ bl,
                                               float* __restrict__ out)
{
    const int b = blockIdx.x;
    const int t = threadIdx.x;
    const float* pb = partial + (long)b * 4 * 128;
    __shared__ float gl[128];
    gl[t] = (pb[t] + pb[128 + t] + pb[256 + t] + pb[384 + t]) * (1.f / NN);
    __syncthreads();
    if (t < NCOUT) {
        float o = bl[t];
        for (int k = 0; k < NH; ++k) o += gl[k] * Wl[k * NCOUT + t];
        out[b * NCOUT + t] = o;
    }
}

extern "C" void kernel_launch(void* const* d_in, const int* in_sizes, int n_in,
                              void* d_out, int out_size, void* d_ws, size_t ws_size,
                              hipStream_t stream)
{
    const float* x    = (const float*)d_in[0];
    const float* adj  = (const float*)d_in[1];
    const float* Wadj = (const float*)d_in[4];
    const float* badj = (const float*)d_in[5];
    const float* W1   = (const float*)d_in[6];
    const float* as1  = (const float*)d_in[7];
    const float* ad1  = (const float*)d_in[8];
    const float* b1   = (const float*)d_in[9];
    const float* W2   = (const float*)d_in[10];
    const float* as2  = (const float*)d_in[11];
    const float* ad2  = (const float*)d_in[12];
    const float* b2   = (const float*)d_in[13];
    const float* lng  = (const float*)d_in[14];
    const float* lnb  = (const float*)d_in[15];
    const float* Wlin = (const float*)d_in[16];
    const float* blin = (const float*)d_in[17];
    float* out = (float*)d_out;

    char* ws = (char*)d_ws;
    unsigned char* maskT = (unsigned char*)ws;        // 256*32*52*128 = 54,525,952
    short* hpT  = (short*)(ws + 54525952);            // 27,262,976 -> 81,788,928
    float* hbuf = (float*)(ws + 81788928);            // 52,428,800 -> 134,217,728
    float* e1sA = (float*)(ws + 134217728);
    float* e2sA = (float*)(ws + 134643712);
    float* e1dA = (float*)(ws + 135069696);
    float* e2dA = (float*)(ws + 135495680);
    short* WtH  = (short*)(ws + 135921664);           // -> 136,347,648
    short* WT1H = (short*)(ws + 136347648);
    short* WT2H = (short*)(ws + 136380416);           // -> 136,413,184
    float* partial = (float*)(ws + 136413184);        // 524,288 -> 136,937,472

    k_wprep<<<dim3(13, 16), dim3(256), 0, stream>>>(Wadj, WtH);
    k_wprepW<<<dim3(64), dim3(256), 0, stream>>>(W1, WT1H);
    k_wprepW<<<dim3(64), dim3(256), 0, stream>>>(W2, WT2H);
    k_mask<<<dim3(4096), dim3(256), 0, stream>>>(adj, WtH, badj, maskT);

    // ---- GAT layer 1 ----
    k_hp<<<dim3(4, NB), dim3(256), 0, stream>>>(x, WT1H, as1, ad1, hpT,
                                                e1sA, e2sA, e1dA, e2dA);
    k_aggr<1><<<dim3(4, NB), dim3(256), 0, stream>>>(maskT, hpT, e1sA, e2sA, e1dA, e2dA,
                                                     b1, lng, lnb, hbuf, partial);

    // ---- GAT layer 2 ----
    k_hp<<<dim3(4, NB), dim3(256), 0, stream>>>(hbuf, WT2H, as2, ad2, hpT,
                                                e1sA, e2sA, e1dA, e2dA);
    k_aggr<1><<<dim3(4, NB), dim3(256), 0, stream>>>(maskT, hpT, e1sA, e2sA, e1dA, e2dA,
                                                     b2, lng, lnb, hbuf, partial);

    // ---- GAT layer 3 (no LN/ReLU; output folded into pool partials) ----
    k_hp<<<dim3(4, NB), dim3(256), 0, stream>>>(hbuf, WT2H, as2, ad2, hpT,
                                                e1sA, e2sA, e1dA, e2dA);
    k_aggr<0><<<dim3(4, NB), dim3(256), 0, stream>>>(maskT, hpT, e1sA, e2sA, e1dA, e2dA,
                                                     b2, lng, lnb, hbuf, partial);

    k_pool2<<<dim3(NB), dim3(128), 0, stream>>>(partial, Wlin, blin, out);
}

// Round 20
// 355.061 us; speedup vs baseline: 1.0351x; 1.0351x over previous
//
#include <hip/hip_runtime.h>
#include <hip/hip_bf16.h>
#include <math.h>

#define NB 256
#define NN 400
#define NH 128
#define NCOUT 16
#define NNP 416   // padded N (13*32 = 52*8)
#define KP  416   // padded K for W_adj prep

static constexpr float LOGIT_THRESH = 0.40546510810816444f; // ln(1.5)
static constexpr float LN_EPS = 1e-5f;

typedef __attribute__((ext_vector_type(8))) short short8v;
typedef __attribute__((ext_vector_type(4))) float f32x4;

static __device__ __forceinline__ short f2bf_rne(float f) {
    unsigned u = __float_as_uint(f);
    unsigned r = (u + 0x7fff + ((u >> 16) & 1)) >> 16;
    return (short)r;
}

// packed f32 pair -> 2x bf16 (RNE) in one v_cvt_pk_bf16_f32
static __device__ __forceinline__ unsigned pk_bf16(float a, float b) {
    __hip_bfloat162 h = __float22bfloat162_rn(make_float2(a, b));
    unsigned r;
    __builtin_memcpy(&r, &h, 4);
    return r;
}
// hi-only conversion of 8 floats -> 8 bf16 (4 cvt_pk)
static __device__ __forceinline__ void cvt8v(const float x[8], short8v& hv) {
    unsigned* hp = (unsigned*)&hv;
#pragma unroll
    for (int q = 0; q < 4; ++q) hp[q] = pk_bf16(x[2 * q], x[2 * q + 1]);
}

// async global->LDS DMA, 16B per lane; lptr is wave-uniform base, HW adds lane*16
static __device__ __forceinline__ void gload16(const void* g, void* l) {
    __builtin_amdgcn_global_load_lds((const __attribute__((address_space(1))) void*)g,
                                     (__attribute__((address_space(3))) void*)l, 16, 0, 0);
}

// ---------------- W_adj -> bf16 (hi only), transposed + padded ----------------
__global__ __launch_bounds__(256) void k_wprep(const float* __restrict__ W,
                                               short* __restrict__ WtH)
{
    const int k0 = blockIdx.x * 32, d0 = blockIdx.y * 32;
    __shared__ float tile[32][33];
    const int t = threadIdx.x, cc = t & 31, rr = t >> 5;
#pragma unroll
    for (int i = 0; i < 4; ++i) {
        int k = k0 + rr + i * 8, d = d0 + cc;
        tile[rr + i * 8][cc] = (k < NN && d < NN) ? W[k * NN + d] : 0.f;
    }
    __syncthreads();
#pragma unroll
    for (int i = 0; i < 4; ++i) {
        int dr = rr + i * 8;
        int d = d0 + dr, k = k0 + cc;
        WtH[d * KP + k] = f2bf_rne(tile[cc][dr]);
    }
}

// ---------------- W (128x128) -> bf16 transposed: WT[h][k] ----------------
__global__ __launch_bounds__(256) void k_wprepW(const float* __restrict__ W,
                                                short* __restrict__ WTH)
{
    const int t = blockIdx.x * 256 + threadIdx.x;   // 16384
    const int h = t >> 7, k = t & 127;
    WTH[h * NH + k] = f2bf_rne(W[k * NH + h]);
}

// ---------------- mask GEMM -> tiled maskT[b][dg][sc][16][8], hi-only bf16 (r13) ----------------
__global__ __launch_bounds__(256) void k_mask(const float* __restrict__ adj,
                                              const short* __restrict__ WtH,
                                              const float* __restrict__ badj,
                                              unsigned char* __restrict__ maskT)
{
    const int j   = blockIdx.x;
    const int xcd = j & 7;
    const int li  = j >> 3;
    const int panel  = xcd * 128 + (li >> 2);
    const int member = li & 3;
    const int b  = panel >> 2;
    const int s0 = (panel & 3) * 128;
    const int d0 = member * 128;

    const int t = threadIdx.x;
    const int lane = t & 63, w = t >> 6;
    const int wm = w >> 1, wn = w & 1;
    const int fr = lane & 15, fc = lane >> 4;

    __shared__ float As[2][128 * 32];
    __shared__ short Bhs[2][128 * 32];

    const float* adjb = adj + (long)b * NN * NN;

    long aG[4];
    int  aRow[4];
#pragma unroll
    for (int i = 0; i < 4; ++i) {
        int rloc = w * 32 + i * 8 + (lane >> 3);
        aRow[i] = rloc;
        int srow = s0 + rloc; srow = srow < NN ? srow : NN - 1;
        int c = (lane & 7) ^ (rloc & 7);
        aG[i] = (long)srow * NN + c * 4;
    }
    long bG[2];
#pragma unroll
    for (int i = 0; i < 2; ++i) {
        int rloc = w * 32 + i * 16 + (lane >> 2);
        int drow = d0 + rloc;
        int c = (lane & 3) ^ ((rloc >> 1) & 3);
        bG[i] = (long)drow * KP + c * 8;
    }

    f32x4 acc[4][4];
#pragma unroll
    for (int mi = 0; mi < 4; ++mi)
#pragma unroll
        for (int ni = 0; ni < 4; ++ni) acc[mi][ni] = (f32x4){0.f, 0.f, 0.f, 0.f};

    const int ca0 = (2 * fc) ^ (fr & 7);
    const int ca1 = (2 * fc + 1) ^ (fr & 7);
    const int cb  = fc ^ ((fr >> 1) & 3);

    #define STAGE(KT, BUF)                                                            \
    do {                                                                              \
        const int k0_ = (KT) * 32;                                                    \
        _Pragma("unroll")                                                             \
        for (int i = 0; i < 4; ++i) {                                                 \
            long gi = aG[i] + k0_;                                                    \
            if ((KT) == 12) {                                                         \
                int c = (lane & 7) ^ (aRow[i] & 7);                                   \
                if (c >= 4) gi = aG[i] - (long)c * 4;                                 \
            }                                                                         \
            gload16(adjb + gi, (char*)&As[BUF][0] + (w * 32 + i * 8) * 128);          \
        }                                                                             \
        _Pragma("unroll")                                                             \
        for (int i = 0; i < 2; ++i) {                                                 \
            gload16(WtH + bG[i] + k0_, (char*)&Bhs[BUF][0] + (w * 32 + i * 16) * 64); \
        }                                                                             \
    } while (0)

    STAGE(0, 0);
    asm volatile("s_waitcnt vmcnt(0)" ::: "memory");
    __builtin_amdgcn_s_barrier();

    int cur = 0;
    for (int kt = 0; kt < 13; ++kt) {
        __builtin_amdgcn_s_barrier();
        if (kt < 12) STAGE(kt + 1, cur ^ 1);
        if (kt < 12) asm volatile("s_waitcnt vmcnt(6)" ::: "memory");
        else         asm volatile("s_waitcnt vmcnt(0)" ::: "memory");
        __builtin_amdgcn_s_barrier();
        __builtin_amdgcn_sched_barrier(0);

        short8v ah[4], bh[4];
#pragma unroll
        for (int m = 0; m < 4; ++m) {
            const int row = wm * 64 + m * 16 + fr;
            float4 u0 = *(const float4*)((const char*)&As[cur][0] + row * 128 + ca0 * 16);
            float4 u1 = *(const float4*)((const char*)&As[cur][0] + row * 128 + ca1 * 16);
            float x[8] = {u0.x, u0.y, u0.z, u0.w, u1.x, u1.y, u1.z, u1.w};
            cvt8v(x, ah[m]);
        }
#pragma unroll
        for (int n = 0; n < 4; ++n) {
            const int row = wn * 64 + n * 16 + fr;
            bh[n] = *(const short8v*)((const char*)&Bhs[cur][0] + row * 64 + cb * 16);
        }
#pragma unroll
        for (int mi = 0; mi < 4; ++mi)
#pragma unroll
            for (int ni = 0; ni < 4; ++ni)
                acc[mi][ni] = __builtin_amdgcn_mfma_f32_16x16x32_bf16(ah[mi], bh[ni], acc[mi][ni], 0, 0, 0);
        cur ^= 1;
    }
    #undef STAGE

    unsigned char* mTb = maskT + (long)b * 32 * 52 * 128;
    const int dgbase = (d0 >> 4) + wn * 4;
    const int scbase = ((s0 + wm * 64) >> 3) + (fc >> 1);
    const int off8   = (fc & 1) * 4;
#pragma unroll
    for (int ni = 0; ni < 4; ++ni) {
        const int d = d0 + wn * 64 + ni * 16 + fr;
        if (d >= NN) continue;
        const float bv = badj[d];
#pragma unroll
        for (int mi = 0; mi < 4; ++mi) {
            const int s_cb = s0 + wm * 64 + mi * 16 + fc * 4;
            if (s_cb >= NNP) continue;
            uchar4 pk;
#pragma unroll
            for (int jj = 0; jj < 4; ++jj) {
                const int s = s_cb + jj;
                bool v = (s < NN) && ((acc[mi][ni][jj] + bv) > LOGIT_THRESH || s == d);
                ((unsigned char*)&pk)[jj] = v ? 1 : 0;
            }
            *(uchar4*)&mTb[((long)(dgbase + ni) * 52 + (scbase + mi * 2)) * 128 + fr * 8 + off8] = pk;
        }
    }
}

// ---------------- hpT (TILED [b][sc][h][8]) = (hin @ W)^T bf16 + FUSED exp tables ----------------
__global__ __launch_bounds__(256) void k_hp(const float* __restrict__ hin,
                                            const short* __restrict__ WTH,
                                            const float* __restrict__ asrc,
                                            const float* __restrict__ adst,
                                            short* __restrict__ hpT,
                                            float* __restrict__ e1sA, float* __restrict__ e2sA,
                                            float* __restrict__ e1dA, float* __restrict__ e2dA)
{
    const int b  = blockIdx.y;
    const int s0 = blockIdx.x * 128;
    const int t  = threadIdx.x;
    const int lane = t & 63, w = t >> 6;
    const int wm = w >> 1, wn = w & 1;
    const int fr = lane & 15, fc = lane >> 4;

    const float* hb = hin + (long)b * NN * NH;
    short* hpTb = hpT + (long)b * 52 * 128 * 8;

    f32x4 acc[4][4];
#pragma unroll
    for (int m = 0; m < 4; ++m)
#pragma unroll
        for (int n = 0; n < 4; ++n) acc[m][n] = (f32x4){0.f, 0.f, 0.f, 0.f};

    for (int kt = 0; kt < 4; ++kt) {
        const int k0 = kt * 32;
        short8v ah[4], bh[4];
#pragma unroll
        for (int m = 0; m < 4; ++m) {
            const int h = wm * 64 + m * 16 + fr;
            ah[m] = *(const short8v*)&WTH[h * NH + k0 + fc * 8];
        }
#pragma unroll
        for (int n = 0; n < 4; ++n) {
            const int s = s0 + wn * 64 + n * 16 + fr;
            float x[8];
            if (s < NN) {
                float4 u0 = *(const float4*)&hb[(long)s * NH + k0 + fc * 8];
                float4 u1 = *(const float4*)&hb[(long)s * NH + k0 + fc * 8 + 4];
                x[0]=u0.x; x[1]=u0.y; x[2]=u0.z; x[3]=u0.w;
                x[4]=u1.x; x[5]=u1.y; x[6]=u1.z; x[7]=u1.w;
            } else {
#pragma unroll
                for (int jj = 0; jj < 8; ++jj) x[jj] = 0.f;
            }
            cvt8v(x, bh[n]);
        }
#pragma unroll
        for (int m = 0; m < 4; ++m)
#pragma unroll
            for (int n = 0; n < 4; ++n)
                acc[m][n] = __builtin_amdgcn_mfma_f32_16x16x32_bf16(ah[m], bh[n], acc[m][n], 0, 0, 0);
    }

    // store: tiled layout [sc][h][8]
#pragma unroll
    for (int m = 0; m < 4; ++m) {
#pragma unroll
        for (int n = 0; n < 4; ++n) {
            const int s = s0 + wn * 64 + n * 16 + fr;
            if (s >= NNP) continue;
            const int sc = s >> 3, so = s & 7;
#pragma unroll
            for (int jj = 0; jj < 4; ++jj) {
                const int h = wm * 64 + m * 16 + fc * 4 + jj;
                hpTb[((long)sc * 128 + h) * 8 + so] = f2bf_rne(acc[m][n][jj]);
            }
        }
    }

    __shared__ float esp[2][128], edp[2][128];
    float asv[4][4], adv[4][4];
#pragma unroll
    for (int m = 0; m < 4; ++m)
#pragma unroll
        for (int jj = 0; jj < 4; ++jj) {
            const int h = wm * 64 + m * 16 + fc * 4 + jj;
            asv[m][jj] = asrc[h];
            adv[m][jj] = adst[h];
        }
    float ps[4] = {0.f, 0.f, 0.f, 0.f}, pd[4] = {0.f, 0.f, 0.f, 0.f};
#pragma unroll
    for (int n = 0; n < 4; ++n)
#pragma unroll
        for (int m = 0; m < 4; ++m)
#pragma unroll
            for (int jj = 0; jj < 4; ++jj) {
                ps[n] += acc[m][n][jj] * asv[m][jj];
                pd[n] += acc[m][n][jj] * adv[m][jj];
            }
#pragma unroll
    for (int n = 0; n < 4; ++n) {
        ps[n] += __shfl_xor(ps[n], 16); ps[n] += __shfl_xor(ps[n], 32);
        pd[n] += __shfl_xor(pd[n], 16); pd[n] += __shfl_xor(pd[n], 32);
    }
    if (fc == 0) {
#pragma unroll
        for (int n = 0; n < 4; ++n) {
            esp[wm][wn * 64 + n * 16 + fr] = ps[n];
            edp[wm][wn * 64 + n * 16 + fr] = pd[n];
        }
    }
    __syncthreads();
    if (t < 128) {
        const int s = s0 + t;
        if (s < NNP) {
            const float es = esp[0][t] + esp[1][t];
            const float ed = edp[0][t] + edp[1][t];
            const long o = (long)b * NNP + s;
            e1sA[o] = __expf(es);       e2sA[o] = __expf(0.2f * es);
            e1dA[o] = __expf(ed);       e2dA[o] = __expf(0.2f * ed);
        }
    }
}

// ---------------- MFMA aggregation v3: tiled-coalesced hpT reads; DO_LN=0 -> fused pool ----------------
template<int DO_LN>
__global__ __launch_bounds__(256) void k_aggr(const unsigned char* __restrict__ maskT,
                                              const short* __restrict__ hpT,
                                              const float* __restrict__ e1sA,
                                              const float* __restrict__ e2sA,
                                              const float* __restrict__ e1dA,
                                              const float* __restrict__ e2dA,
                                              const float* __restrict__ bias,
                                              const float* __restrict__ lng,
                                              const float* __restrict__ lnb,
                                              float* __restrict__ hout,
                                              float* __restrict__ partial)
{
    const int b  = blockIdx.y;
    const int bx = blockIdx.x;
    const int d0 = bx * 128;
    const int t  = threadIdx.x;
    const int lane = t & 63, w = t >> 6;       // w = d-quarter
    const int fr = lane & 15, fc = lane >> 4;

    __shared__ float e1s_l[NNP], e2s_l[NNP];
    __shared__ float den_l[128];
    __shared__ float lngl[128], lnbl[128];
    __shared__ float wsum[4][128];

    for (int i = t; i < NNP; i += 256) {
        const long o = (long)b * NNP + i;
        e1s_l[i] = e1sA[o];
        e2s_l[i] = e2sA[o];
    }
    if (DO_LN && t < 128) { lngl[t] = lng[t]; lnbl[t] = lnb[t]; }

    float e1dv[2], e2dv[2];
#pragma unroll
    for (int m = 0; m < 2; ++m) {
        const int d = d0 + w * 32 + m * 16 + fr;
        const bool v = d < NN;
        const long o = (long)b * NNP + (v ? d : 0);
        e1dv[m] = v ? e1dA[o] : 0.f;
        e2dv[m] = v ? e2dA[o] : 0.f;
    }
    __syncthreads();

    f32x4 acc[2][8];
#pragma unroll
    for (int m = 0; m < 2; ++m)
#pragma unroll
        for (int n = 0; n < 8; ++n) acc[m][n] = (f32x4){0.f, 0.f, 0.f, 0.f};
    float den[2] = {0.f, 0.f};

    const unsigned char* mbase = maskT + (((long)b * 32 + (d0 >> 4) + w * 2) * 52) * 128 + fr * 8;
    const short* hTb = hpT + (long)b * 52 * 128 * 8;

    for (int kt = 0; kt < 13; ++kt) {
        const int sb = kt * 32 + fc * 8;
        const short* tb = hTb + (long)(kt * 4 + fc) * 128 * 8;   // tile sc = kt*4+fc
        short8v bf_[8];
#pragma unroll
        for (int n = 0; n < 8; ++n)
            bf_[n] = *(const short8v*)&tb[(n * 16 + fr) * 8];    // 256B/16-lane group
        float4 e1a = *(const float4*)&e1s_l[sb];
        float4 e1b = *(const float4*)&e1s_l[sb + 4];
        float4 e2a = *(const float4*)&e2s_l[sb];
        float4 e2b = *(const float4*)&e2s_l[sb + 4];
        float e18[8] = {e1a.x, e1a.y, e1a.z, e1a.w, e1b.x, e1b.y, e1b.z, e1b.w};
        float e28[8] = {e2a.x, e2a.y, e2a.z, e2a.w, e2b.x, e2b.y, e2b.z, e2b.w};
        const long scoff = (long)(kt * 4 + fc) * 128;
#pragma unroll
        for (int m = 0; m < 2; ++m) {
            const unsigned long long mk = *(const unsigned long long*)(mbase + (long)m * 52 * 128 + scoff);
            short8v pv;
            unsigned* pw = (unsigned*)&pv;
#pragma unroll
            for (int q = 0; q < 4; ++q) {
                float p0 = fmaxf(e18[2 * q] * e1dv[m],     e28[2 * q] * e2dv[m]);
                float p1 = fmaxf(e18[2 * q + 1] * e1dv[m], e28[2 * q + 1] * e2dv[m]);
                p0 = ((mk >> (16 * q)) & 0xffULL)     ? p0 : 0.f;
                p1 = ((mk >> (16 * q + 8)) & 0xffULL) ? p1 : 0.f;
                den[m] += p0 + p1;
                pw[q] = pk_bf16(p0, p1);
            }
#pragma unroll
            for (int n = 0; n < 8; ++n)
                acc[m][n] = __builtin_amdgcn_mfma_f32_16x16x32_bf16(pv, bf_[n], acc[m][n], 0, 0, 0);
        }
    }

#pragma unroll
    for (int m = 0; m < 2; ++m) {
        den[m] += __shfl_xor(den[m], 16);
        den[m] += __shfl_xor(den[m], 32);
    }
    if (fc == 0) {
#pragma unroll
        for (int m = 0; m < 2; ++m) den_l[w * 32 + m * 16 + fr] = den[m];
    }
    __syncthreads();

    float bvh[8], lgv[8], lbv[8];
#pragma unroll
    for (int n = 0; n < 8; ++n) {
        bvh[n] = bias[n * 16 + fr];
        if (DO_LN) { lgv[n] = lngl[n * 16 + fr]; lbv[n] = lnbl[n * 16 + fr]; }
    }

    float* hb = hout + (long)b * NN * NH;

    if (DO_LN) {
#pragma unroll
        for (int m = 0; m < 2; ++m) {
#pragma unroll
            for (int jj = 0; jj < 4; ++jj) {
                const int dl = w * 32 + m * 16 + fc * 4 + jj;
                const int d = d0 + dl;
                const float idn = 1.f / den_l[dl];
                float v[8];
                float s1 = 0.f, s2 = 0.f;
#pragma unroll
                for (int n = 0; n < 8; ++n) {
                    v[n] = acc[m][n][jj] * idn + bvh[n];
                    s1 += v[n];
                    s2 += v[n] * v[n];
                }
                s1 += __shfl_xor(s1, 1); s2 += __shfl_xor(s2, 1);
                s1 += __shfl_xor(s1, 2); s2 += __shfl_xor(s2, 2);
                s1 += __shfl_xor(s1, 4); s2 += __shfl_xor(s2, 4);
                s1 += __shfl_xor(s1, 8); s2 += __shfl_xor(s2, 8);
                const float mean = s1 * (1.f / 128.f);
                const float var  = s2 * (1.f / 128.f) - mean * mean;
                const float inv  = rsqrtf(fmaxf(var, 0.f) + LN_EPS);
                if (d < NN) {
                    float* po = hb + (long)d * NH;
#pragma unroll
                    for (int n = 0; n < 8; ++n)
                        po[n * 16 + fr] = fmaxf((v[n] - mean) * inv * lgv[n] + lbv[n], 0.f);
                }
            }
        }
    } else {
        float psum[8] = {0.f, 0.f, 0.f, 0.f, 0.f, 0.f, 0.f, 0.f};
#pragma unroll
        for (int m = 0; m < 2; ++m) {
#pragma unroll
            for (int jj = 0; jj < 4; ++jj) {
                const int dl = w * 32 + m * 16 + fc * 4 + jj;
                const int d = d0 + dl;
                if (d >= NN) continue;
                const float idn = 1.f / den_l[dl];
#pragma unroll
                for (int n = 0; n < 8; ++n)
                    psum[n] += acc[m][n][jj] * idn + bvh[n];
            }
        }
#pragma unroll
        for (int n = 0; n < 8; ++n) {
            psum[n] += __shfl_xor(psum[n], 16);
            psum[n] += __shfl_xor(psum[n], 32);
        }
        if (fc == 0) {
#pragma unroll
            for (int n = 0; n < 8; ++n) wsum[w][n * 16 + fr] = psum[n];
        }
        __syncthreads();
        if (t < 128)
            partial[((long)b * 4 + bx) * 128 + t] =
                wsum[0][t] + wsum[1][t] + wsum[2][t] + wsum[3][t];
    }
}

// ---------------- final: mean over N (from partials) + linear ----------------
__global__ __launch_bounds__(128) void k_pool2(const float* __restrict__ partial,
                                               const float* __restrict__ Wl,
                                               const float* __restrict__ bl,
                                               float* __restrict__ out)
{
    const int b = blockIdx.x;
    const int t = threadIdx.x;
    const float* pb = partial + (long)b * 4 * 128;
    __shared__ float gl[128];
    gl[t] = (pb[t] + pb[128 + t] + pb[256 + t] + pb[384 + t]) * (1.f / NN);
    __syncthreads();
    if (t < NCOUT) {
        float o = bl[t];
        for (int k = 0; k < NH; ++k) o += gl[k] * Wl[k * NCOUT + t];
        out[b * NCOUT + t] = o;
    }
}

extern "C" void kernel_launch(void* const* d_in, const int* in_sizes, int n_in,
                              void* d_out, int out_size, void* d_ws, size_t ws_size,
                              hipStream_t stream)
{
    const float* x    = (const float*)d_in[0];
    const float* adj  = (const float*)d_in[1];
    const float* Wadj = (const float*)d_in[4];
    const float* badj = (const float*)d_in[5];
    const float* W1   = (const float*)d_in[6];
    const float* as1  = (const float*)d_in[7];
    const float* ad1  = (const float*)d_in[8];
    const float* b1   = (const float*)d_in[9];
    const float* W2   = (const float*)d_in[10];
    const float* as2  = (const float*)d_in[11];
    const float* ad2  = (const float*)d_in[12];
    const float* b2   = (const float*)d_in[13];
    const float* lng  = (const float*)d_in[14];
    const float* lnb  = (const float*)d_in[15];
    const float* Wlin = (const float*)d_in[16];
    const float* blin = (const float*)d_in[17];
    float* out = (float*)d_out;

    char* ws = (char*)d_ws;
    unsigned char* maskT = (unsigned char*)ws;        // 256*32*52*128 = 54,525,952
    short* hpT  = (short*)(ws + 54525952);            // 27,262,976 -> 81,788,928
    float* hbuf = (float*)(ws + 81788928);            // 52,428,800 -> 134,217,728
    float* e1sA = (float*)(ws + 134217728);
    float* e2sA = (float*)(ws + 134643712);
    float* e1dA = (float*)(ws + 135069696);
    float* e2dA = (float*)(ws + 135495680);
    short* WtH  = (short*)(ws + 135921664);           // -> 136,347,648
    short* WT1H = (short*)(ws + 136347648);
    short* WT2H = (short*)(ws + 136380416);           // -> 136,413,184
    float* partial = (float*)(ws + 136413184);        // 524,288 -> 136,937,472

    k_wprep<<<dim3(13, 16), dim3(256), 0, stream>>>(Wadj, WtH);
    k_wprepW<<<dim3(64), dim3(256), 0, stream>>>(W1, WT1H);
    k_wprepW<<<dim3(64), dim3(256), 0, stream>>>(W2, WT2H);
    k_mask<<<dim3(4096), dim3(256), 0, stream>>>(adj, WtH, badj, maskT);

    // ---- GAT layer 1 ----
    k_hp<<<dim3(4, NB), dim3(256), 0, stream>>>(x, WT1H, as1, ad1, hpT,
                                                e1sA, e2sA, e1dA, e2dA);
    k_aggr<1><<<dim3(4, NB), dim3(256), 0, stream>>>(maskT, hpT, e1sA, e2sA, e1dA, e2dA,
                                                     b1, lng, lnb, hbuf, partial);

    // ---- GAT layer 2 ----
    k_hp<<<dim3(4, NB), dim3(256), 0, stream>>>(hbuf, WT2H, as2, ad2, hpT,
                                                e1sA, e2sA, e1dA, e2dA);
    k_aggr<1><<<dim3(4, NB), dim3(256), 0, stream>>>(maskT, hpT, e1sA, e2sA, e1dA, e2dA,
                                                     b2, lng, lnb, hbuf, partial);

    // ---- GAT layer 3 (no LN/ReLU; output folded into pool partials) ----
    k_hp<<<dim3(4, NB), dim3(256), 0, stream>>>(hbuf, WT2H, as2, ad2, hpT,
                                                e1sA, e2sA, e1dA, e2dA);
    k_aggr<0><<<dim3(4, NB), dim3(256), 0, stream>>>(maskT, hpT, e1sA, e2sA, e1dA, e2dA,
                                                     b2, lng, lnb, hbuf, partial);

    k_pool2<<<dim3(NB), dim3(128), 0, stream>>>(partial, Wlin, blin, out);
}